// Round 1
// baseline (617.006 us; speedup 1.0000x reference)
//
#include <hip/hip_runtime.h>
#include <hip/hip_bf16.h>

typedef __hip_bfloat16 bf16;
typedef __attribute__((ext_vector_type(4))) float f32x4;
typedef __attribute__((ext_vector_type(8))) short s16x8;

#define DEV static __device__ __forceinline__

namespace {

constexpr float kEPS = 1e-5f;
constexpr float kFACTOR = 1.0f / 112.0f;  // 1/sqrt(196*64), 112^2 = 12544

DEV float hswish_f(float v) { return v * fminf(fmaxf(v + 3.f, 0.f), 6.f) * (1.f / 6.f); }

// ---- K0: convert pointwise weights fp32 -> bf16 --------------------------
__global__ void cvt_pw_kernel(const float* __restrict__ a,
                              const float* __restrict__ b,
                              const float* __restrict__ c,
                              bf16* __restrict__ oa, bf16* __restrict__ ob,
                              bf16* __restrict__ oc) {
  int i = blockIdx.x * 256 + threadIdx.x;
  if (i < 512 * 256) {
    oa[i] = __float2bfloat16(a[i]);
    ob[i] = __float2bfloat16(b[i]);
  }
  if (i < 2048 * 256) oc[i] = __float2bfloat16(c[i]);
}

// ---- K1: depthwise conv(1,3,3)+BN+hswish, 3 branches ---------------------
// writes h[n][t*196+s][c] bf16 (c contiguous -> GEMM B operand K-contiguous)
__global__ __launch_bounds__(256) void conv_kernel(
    const float* __restrict__ x,
    const float* __restrict__ tdw, const float* __restrict__ tg,
    const float* __restrict__ tb, const float* __restrict__ tm, const float* __restrict__ tv,
    const float* __restrict__ pdw, const float* __restrict__ pg,
    const float* __restrict__ pb, const float* __restrict__ pm, const float* __restrict__ pv,
    const float* __restrict__ gdw, const float* __restrict__ gG,
    const float* __restrict__ gb, const float* __restrict__ gm, const float* __restrict__ gv,
    bf16* __restrict__ h_t, bf16* __restrict__ h_p, bf16* __restrict__ h_g) {
  int bid = blockIdx.x;
  int cb = bid & 3, t = (bid >> 2) & 15, n = bid >> 6;
  int c0 = cb * 64;
  __shared__ float xs[64][197];  // pad 197: (197%32)=5, gcd=1 -> 2-way max
  __shared__ float wts[3][64][9];
  __shared__ float sc[3][64], sh[3][64];
  int tid = threadIdx.x;
  for (int i = tid; i < 64 * 9; i += 256) {
    int cl = i / 9, k = i % 9;
    wts[0][cl][k] = tdw[(c0 + cl) * 9 + k];
    wts[1][cl][k] = pdw[(c0 + cl) * 9 + k];
    wts[2][cl][k] = gdw[(c0 + cl) * 9 + k];
  }
  if (tid < 64) {
    int c = c0 + tid;
    float s0 = tg[c] * rsqrtf(tv[c] + kEPS);
    sc[0][tid] = s0; sh[0][tid] = tb[c] - tm[c] * s0;
    float s1 = pg[c] * rsqrtf(pv[c] + kEPS);
    sc[1][tid] = s1; sh[1][tid] = pb[c] - pm[c] * s1;
    float s2 = gG[c] * rsqrtf(gv[c] + kEPS);
    sc[2][tid] = s2; sh[2][tid] = gb[c] - gm[c] * s2;
  }
  const float* xb = x + ((size_t)(n * 256 + c0) * 16 + t) * 196;
  for (int i = tid; i < 64 * 196; i += 256) {
    int cl = i / 196, s = i % 196;
    xs[cl][s] = xb[(size_t)cl * 3136 + s];
  }
  __syncthreads();
  for (int i = tid; i < 64 * 196; i += 256) {
    int cl = i & 63, sp = i >> 6;        // cl fastest -> coalesced h writes
    int hs = sp / 14, wsp = sp % 14;
    float a0 = 0.f, a1 = 0.f, a2 = 0.f;
    #pragma unroll
    for (int dy = -1; dy <= 1; ++dy) {
      int yy = hs + dy;
      if (yy < 0 || yy >= 14) continue;
      #pragma unroll
      for (int dx = -1; dx <= 1; ++dx) {
        int xx = wsp + dx;
        if (xx < 0 || xx >= 14) continue;
        float v = xs[cl][yy * 14 + xx];
        int k = (dy + 1) * 3 + (dx + 1);
        a0 = fmaf(wts[0][cl][k], v, a0);
        a1 = fmaf(wts[1][cl][k], v, a1);
        a2 = fmaf(wts[2][cl][k], v, a2);
      }
    }
    a0 = hswish_f(a0 * sc[0][cl] + sh[0][cl]);
    a1 = hswish_f(a1 * sc[1][cl] + sh[1][cl]);
    a2 = hswish_f(a2 * sc[2][cl] + sh[2][cl]);
    size_t oidx = ((size_t)n * 3136 + t * 196 + sp) * 256 + c0 + cl;
    h_t[oidx] = __float2bfloat16(a0);
    h_p[oidx] = __float2bfloat16(a1);
    h_g[oidx] = __float2bfloat16(a2);
  }
}

// ---- K2: bf16 MFMA GEMM  D[n][o][ts] = sum_c A[o][c]*B[n][ts][c] ---------
// EPI=0: +bias(e0)   EPI=1: bn2(e0..e3)+hswish
template <int EPI>
__global__ __launch_bounds__(256) void gemm_kernel(
    const bf16* __restrict__ A,  // [M][256]
    const bf16* __restrict__ B,  // [8][3136][256]
    bf16* __restrict__ D,        // [8][M][3136]
    const float* __restrict__ e0, const float* __restrict__ e1,
    const float* __restrict__ e2, const float* __restrict__ e3, int M) {
  int mt = blockIdx.x, nt = blockIdx.y, n = blockIdx.z;
  __shared__ __align__(16) bf16 lds_a[128 * 64];
  __shared__ __align__(16) bf16 lds_b[64 * 64];
  int tid = threadIdx.x;
  int wid = tid >> 6, lane = tid & 63;
  int wr = wid >> 1, wc = wid & 1;
  int l15 = lane & 15, lh = lane >> 4;
  f32x4 acc[4][2];
  #pragma unroll
  for (int m = 0; m < 4; ++m)
    #pragma unroll
    for (int q = 0; q < 2; ++q) acc[m][q] = (f32x4){0.f, 0.f, 0.f, 0.f};
  const bf16* Ab = A + (size_t)mt * 128 * 256;
  const bf16* Bb = B + ((size_t)n * 3136 + (size_t)nt * 64) * 256;
  for (int k0 = 0; k0 < 256; k0 += 64) {
    #pragma unroll
    for (int it = 0; it < 4; ++it) {
      int g = tid + it * 256;            // 1024 granules of 16B (A: 128x64)
      int row = g >> 3, c16 = g & 7;
      int4 v = *(const int4*)(Ab + (size_t)row * 256 + k0 + c16 * 8);
      *(int4*)((char*)lds_a + row * 128 + ((c16 * 16) ^ ((row & 7) << 4))) = v;
    }
    #pragma unroll
    for (int it = 0; it < 2; ++it) {
      int g = tid + it * 256;            // 512 granules (B: 64x64)
      int row = g >> 3, c16 = g & 7;
      int4 v = *(const int4*)(Bb + (size_t)row * 256 + k0 + c16 * 8);
      *(int4*)((char*)lds_b + row * 128 + ((c16 * 16) ^ ((row & 7) << 4))) = v;
    }
    __syncthreads();
    #pragma unroll
    for (int kk = 0; kk < 64; kk += 32) {
      s16x8 af[4], bfr[2];
      #pragma unroll
      for (int m = 0; m < 4; ++m) {
        int row = wr * 64 + m * 16 + l15;
        af[m] = *(const s16x8*)((const char*)lds_a + row * 128 +
                                (((kk + lh * 8) * 2) ^ ((row & 7) << 4)));
      }
      #pragma unroll
      for (int q = 0; q < 2; ++q) {
        int row = wc * 32 + q * 16 + l15;
        bfr[q] = *(const s16x8*)((const char*)lds_b + row * 128 +
                                 (((kk + lh * 8) * 2) ^ ((row & 7) << 4)));
      }
      #pragma unroll
      for (int m = 0; m < 4; ++m)
        #pragma unroll
        for (int q = 0; q < 2; ++q)
          acc[m][q] = __builtin_amdgcn_mfma_f32_16x16x32_bf16(af[m], bfr[q], acc[m][q], 0, 0, 0);
    }
    __syncthreads();
  }
  #pragma unroll
  for (int m = 0; m < 4; ++m) {
    #pragma unroll
    for (int q = 0; q < 2; ++q) {
      int col = nt * 64 + wc * 32 + q * 16 + l15;
      #pragma unroll
      for (int r = 0; r < 4; ++r) {
        int orow = mt * 128 + wr * 64 + m * 16 + lh * 4 + r;  // m89 C/D layout
        float v = acc[m][q][r];
        if (EPI == 0) {
          v += e0[orow];
        } else {
          float scl = e0[orow] * rsqrtf(e3[orow] + kEPS);
          v = (v - e2[orow]) * scl + e1[orow];
          v = hswish_f(v);
        }
        D[((size_t)n * M + orow) * 3136 + col] = __float2bfloat16(v);
      }
    }
  }
}

// ---- K3: adjacency logits, partial over e-blocks (atomicAdd) -------------
__global__ __launch_bounds__(256) void adj_accum_kernel(const bf16* __restrict__ th,
                                                        const bf16* __restrict__ ph,
                                                        float* __restrict__ adj_raw) {
  int bid = blockIdx.x;
  int eb = bid & 7, h = (bid >> 3) & 7, n = bid >> 6;
  __shared__ __align__(16) float As[16 * 196];
  __shared__ __align__(16) float Bs[16 * 196];
  int tid = threadIdx.x;
  int t = tid >> 4, u = tid & 15;
  float acc = 0.f;
  for (int e8 = 0; e8 < 8; ++e8) {
    int e = eb * 8 + e8;
    const bf16* tp = th + ((size_t)n * 512 + h * 64 + e) * 3136;
    const bf16* pp = ph + ((size_t)n * 512 + h * 64 + e) * 3136;
    __syncthreads();
    for (int i = tid; i < 3136; i += 256) {
      As[i] = __bfloat162float(tp[i]);
      Bs[i] = __bfloat162float(pp[i]);
    }
    __syncthreads();
    const float* ar = As + t * 196;
    const float* br = Bs + u * 196;
    #pragma unroll
    for (int j = 0; j < 49; ++j) {
      f32x4 a = *(const f32x4*)(ar + j * 4);
      f32x4 b = *(const f32x4*)(br + j * 4);
      acc = fmaf(a[0], b[0], acc); acc = fmaf(a[1], b[1], acc);
      acc = fmaf(a[2], b[2], acc); acc = fmaf(a[3], b[3], acc);
    }
  }
  atomicAdd(&adj_raw[((n * 8 + h) * 16 + t) * 16 + u], acc);
}

// ---- K3b: softmax over u (16), with FACTOR -------------------------------
__global__ void adj_softmax_kernel(const float* __restrict__ raw, float* __restrict__ adj) {
  int r = blockIdx.x * 256 + threadIdx.x;
  if (r >= 1024) return;
  const float* p = raw + r * 16;
  float* q = adj + r * 16;
  float v[16], mx = -1e30f;
  #pragma unroll
  for (int u = 0; u < 16; ++u) { v[u] = p[u] * kFACTOR; mx = fmaxf(mx, v[u]); }
  float s = 0.f;
  #pragma unroll
  for (int u = 0; u < 16; ++u) { v[u] = __expf(v[u] - mx); s += v[u]; }
  float inv = 1.f / s;
  #pragma unroll
  for (int u = 0; u < 16; ++u) q[u] = v[u] * inv;
}

// ---- K4: hf[n][t][h] = sum_{c,s} hswish(sum_u adj*gg) (mean applied later)
__global__ __launch_bounds__(256) void hf_kernel(const bf16* __restrict__ gg,
                                                 const float* __restrict__ adj,
                                                 float* __restrict__ hf) {
  int bid = blockIdx.x;
  int n = bid >> 11, o = bid & 2047, h = o >> 8;
  __shared__ float adjL[256];
  __shared__ float red[16][4];
  int tid = threadIdx.x;
  adjL[tid] = adj[(n * 8 + h) * 256 + tid];
  __syncthreads();
  float ts[16];
  #pragma unroll
  for (int t = 0; t < 16; ++t) ts[t] = 0.f;
  if (tid < 196) {
    const bf16* gp = gg + ((size_t)n * 2048 + o) * 3136 + tid;
    float gv[16];
    #pragma unroll
    for (int u = 0; u < 16; ++u) gv[u] = __bfloat162float(gp[u * 196]);
    #pragma unroll
    for (int t = 0; t < 16; ++t) {
      float p = 0.f;
      #pragma unroll
      for (int u = 0; u < 16; ++u) p = fmaf(adjL[t * 16 + u], gv[u], p);
      ts[t] = hswish_f(p);
    }
  }
  #pragma unroll
  for (int t = 0; t < 16; ++t) {
    float v = ts[t];
    #pragma unroll
    for (int off = 32; off > 0; off >>= 1) v += __shfl_down(v, off);
    if ((tid & 63) == 0) red[t][tid >> 6] = v;
  }
  __syncthreads();
  if (tid < 16) {
    float v = red[tid][0] + red[tid][1] + red[tid][2] + red[tid][3];
    atomicAdd(&hf[(n * 16 + tid) * 8 + h], v);
  }
}

// ---- K5: head-mix attn = softmax(hf_mean @ heads_w) ----------------------
__global__ void attn_kernel(const float* __restrict__ hf, const float* __restrict__ hw,
                            float* __restrict__ attn) {
  int tid = threadIdx.x;
  if (tid >= 128) return;
  int n = tid >> 4, t = tid & 15;
  const float inv = 1.0f / (256.0f * 196.0f);
  float hm[8];
  #pragma unroll
  for (int h = 0; h < 8; ++h) hm[h] = hf[(n * 16 + t) * 8 + h] * inv;
  float o[8], mx = -1e30f;
  #pragma unroll
  for (int h2 = 0; h2 < 8; ++h2) {
    float s = 0.f;
    #pragma unroll
    for (int h = 0; h < 8; ++h) s = fmaf(hm[h], hw[h * 8 + h2], s);
    o[h2] = s; mx = fmaxf(mx, s);
  }
  float s = 0.f;
  #pragma unroll
  for (int h2 = 0; h2 < 8; ++h2) { o[h2] = __expf(o[h2] - mx); s += o[h2]; }
  float is = 1.f / s;
  #pragma unroll
  for (int h2 = 0; h2 < 8; ++h2) attn[(n * 16 + t) * 8 + h2] = o[h2] * is;
}

// ---- K6: z + residual + final hswish (recomputes gcn elementwise) --------
__global__ __launch_bounds__(256) void out_kernel(const bf16* __restrict__ gg,
                                                  const float* __restrict__ adj,
                                                  const float* __restrict__ attn,
                                                  const float* __restrict__ x,
                                                  float* __restrict__ out) {
  int bid = blockIdx.x;
  int n = bid >> 8, c = bid & 255;
  __shared__ float adjL[8][256];
  __shared__ float atL[16][8];
  int tid = threadIdx.x;
  for (int i = tid; i < 2048; i += 256) adjL[i >> 8][i & 255] = adj[n * 2048 + i];
  if (tid < 128) atL[tid >> 3][tid & 7] = attn[n * 128 + tid];
  __syncthreads();
  if (tid >= 196) return;
  float acc[16];
  #pragma unroll
  for (int t = 0; t < 16; ++t) acc[t] = 0.f;
  #pragma unroll
  for (int h = 0; h < 8; ++h) {
    const bf16* gp = gg + ((size_t)n * 2048 + h * 256 + c) * 3136 + tid;
    float gv[16];
    #pragma unroll
    for (int u = 0; u < 16; ++u) gv[u] = __bfloat162float(gp[u * 196]);
    #pragma unroll
    for (int t = 0; t < 16; ++t) {
      float p = 0.f;
      #pragma unroll
      for (int u = 0; u < 16; ++u) p = fmaf(adjL[h][t * 16 + u], gv[u], p);
      acc[t] = fmaf(atL[t][h], hswish_f(p), acc[t]);
    }
  }
  const float* xp = x + ((size_t)n * 256 + c) * 3136 + tid;
  float* op = out + ((size_t)n * 256 + c) * 3136 + tid;
  #pragma unroll
  for (int t = 0; t < 16; ++t) op[t * 196] = hswish_f(xp[t * 196] + acc[t]);
}

}  // namespace

extern "C" void kernel_launch(void* const* d_in, const int* in_sizes, int n_in,
                              void* d_out, int out_size, void* d_ws, size_t ws_size,
                              hipStream_t stream) {
  const float* x       = (const float*)d_in[0];
  const float* t_dw    = (const float*)d_in[1];
  const float* t_g     = (const float*)d_in[2];
  const float* t_b     = (const float*)d_in[3];
  const float* t_m     = (const float*)d_in[4];
  const float* t_v     = (const float*)d_in[5];
  const float* t_pw    = (const float*)d_in[6];
  const float* p_dw    = (const float*)d_in[7];
  const float* p_g     = (const float*)d_in[8];
  const float* p_b     = (const float*)d_in[9];
  const float* p_m     = (const float*)d_in[10];
  const float* p_v     = (const float*)d_in[11];
  const float* p_pw    = (const float*)d_in[12];
  const float* g_dw    = (const float*)d_in[13];
  const float* g_g     = (const float*)d_in[14];
  const float* g_b     = (const float*)d_in[15];
  const float* g_m     = (const float*)d_in[16];
  const float* g_v     = (const float*)d_in[17];
  const float* g_pw    = (const float*)d_in[18];
  const float* t_pb    = (const float*)d_in[19];
  const float* p_pb    = (const float*)d_in[20];
  const float* g2_g    = (const float*)d_in[21];
  const float* g2_b    = (const float*)d_in[22];
  const float* g2_m    = (const float*)d_in[23];
  const float* g2_v    = (const float*)d_in[24];
  const float* heads_w = (const float*)d_in[25];
  float* out = (float*)d_out;
  (void)in_sizes; (void)n_in; (void)out_size; (void)ws_size;

  char* w = (char*)d_ws;
  size_t off = 0;
  auto take = [&](size_t bytes) {
    char* p = w + off;
    off = (off + bytes + 255) & ~(size_t)255;
    return p;
  };
  bf16* pwT = (bf16*)take(512 * 256 * 2);
  bf16* pwP = (bf16*)take(512 * 256 * 2);
  bf16* pwG = (bf16*)take(2048 * 256 * 2);
  bf16* hT  = (bf16*)take((size_t)8 * 3136 * 256 * 2);
  bf16* hP  = (bf16*)take((size_t)8 * 3136 * 256 * 2);
  bf16* hG  = (bf16*)take((size_t)8 * 3136 * 256 * 2);
  bf16* th  = (bf16*)take((size_t)8 * 512 * 3136 * 2);
  bf16* ph  = (bf16*)take((size_t)8 * 512 * 3136 * 2);
  bf16* gg  = (bf16*)take((size_t)8 * 2048 * 3136 * 2);
  float* adj_raw = (float*)take(1024 * 16 * 4);
  float* adj     = (float*)take(1024 * 16 * 4);
  float* hf      = (float*)take(1024 * 4);
  float* attn    = (float*)take(1024 * 4);

  hipMemsetAsync(adj_raw, 0, 1024 * 16 * 4, stream);
  hipMemsetAsync(hf, 0, 1024 * 4, stream);

  cvt_pw_kernel<<<2048, 256, 0, stream>>>(t_pw, p_pw, g_pw, pwT, pwP, pwG);
  conv_kernel<<<512, 256, 0, stream>>>(x, t_dw, t_g, t_b, t_m, t_v,
                                       p_dw, p_g, p_b, p_m, p_v,
                                       g_dw, g_g, g_b, g_m, g_v, hT, hP, hG);
  gemm_kernel<0><<<dim3(4, 49, 8), 256, 0, stream>>>(pwT, hT, th, t_pb, nullptr, nullptr, nullptr, 512);
  gemm_kernel<0><<<dim3(4, 49, 8), 256, 0, stream>>>(pwP, hP, ph, p_pb, nullptr, nullptr, nullptr, 512);
  gemm_kernel<1><<<dim3(16, 49, 8), 256, 0, stream>>>(pwG, hG, gg, g2_g, g2_b, g2_m, g2_v, 2048);
  adj_accum_kernel<<<512, 256, 0, stream>>>(th, ph, adj_raw);
  adj_softmax_kernel<<<4, 256, 0, stream>>>(adj_raw, adj);
  hf_kernel<<<16384, 256, 0, stream>>>(gg, adj, hf);
  attn_kernel<<<1, 128, 0, stream>>>(hf, heads_w, attn);
  out_kernel<<<2048, 256, 0, stream>>>(gg, adj, attn, x, out);
}